// Round 12
// baseline (28.929 us; speedup 1.0000x reference)
//
#include <hip/hip_runtime.h>
#include <math.h>

#define B_ 4
#define N_ 32768
#define M_ 8192
#define K_ 16
#define D_ 64
#define O_ 64

typedef __attribute__((ext_vector_type(8))) short bf16x8;
typedef __attribute__((ext_vector_type(4))) float f32x4;

// float -> bf16 bits, round-to-nearest-even (inputs are finite normals)
static __device__ __forceinline__ short f2bf(float f) {
    unsigned u = __float_as_uint(f);
    u += 0x7fffu + ((u >> 16) & 1u);
    return (short)(u >> 16);
}

static __device__ __forceinline__ bf16x8 cvt_bf8(float4 f0, float4 f1) {
    bf16x8 v;
    v[0] = f2bf(f0.x); v[1] = f2bf(f0.y); v[2] = f2bf(f0.z); v[3] = f2bf(f0.w);
    v[4] = f2bf(f1.x); v[5] = f2bf(f1.y); v[6] = f2bf(f1.z); v[7] = f2bf(f1.w);
    return v;
}

// 8 consecutive floats -> bf16x8 (one MFMA k-chunk)
static __device__ __forceinline__ bf16x8 ld_bf8(const float* p) {
    return cvt_bf8(*(const float4*)p, *(const float4*)(p + 4));
}

// ---------------------------------------------------------------------------
// Fused kernel (R12 = R11 + register budget + explicit gather pipeline):
//   out[b,o,m] = relu( max_k (x[b,idx[m,k]].W1[o]) + xs[b,m].(W2-W1)[o] + b[o] )
// R11 counters: VGPR=68 — too small to hold the 64-VGPR W-frag set, so the
// compiler re-read frags from LDS every m (ds_read back on the MFMA critical
// path) and had no regs to prefetch gathers. Grid caps occupancy at 2
// waves/SIMD regardless, so VGPRs are free up to 256:
//   1) __launch_bounds__(256, 2)  -> VGPR cap 256, same occupancy.
//   2) distance-3 software prefetch of raw float4 gathers in the fully
//      unrolled m-loop (static indexing; ~3 gathers in flight per wave).
// Structure otherwise = R11: 512 blocks x 4 waves, wave = 16 m; idx hoisted
// to VGPRs; W frags staged via LDS once (wave wv converts o-tile wv).
// ---------------------------------------------------------------------------
__global__ __launch_bounds__(256, 2)
void fused_gconv(const float* __restrict__ x, const float* __restrict__ xs,
                 const int* __restrict__ idx, const float* __restrict__ W,
                 const float* __restrict__ bias, float* __restrict__ out) {
    __shared__ int    ldsI[64 * 16];         // 4 KB: 64 m x 16 k
    __shared__ bf16x8 ldsW[4][2][2][64];     // 16 KB: [t][s][b1/bd][lane]
    __shared__ float  ldsB[64];
    __shared__ float  ldsT[64 * 65];         // transpose, stride 65

    const int tid  = threadIdx.x;
    const int blk  = blockIdx.x;       // 0..511
    const int bb   = blk >> 7;         // batch
    const int mblk = (blk & 127) * 64; // batch-local m base of block

    // stage idx: 4KB, fully coalesced (256 thr x int4)
    *(int4*)&ldsI[tid * 4] =
        *(const int4*)(idx + ((size_t)bb * M_ + mblk) * 16 + tid * 4);

    const int l  = tid & 63;
    const int wv = tid >> 6;           // wave id -> 16-m group, and W t-slice
    const int lr = l & 15;             // fragment row / col
    const int kg = l >> 4;             // k-group
    const int mw = wv * 16;            // group base within block

    // ---- W-frag stage: wave wv converts o-tile t=wv (b1 = W1, bd = W2-W1)
    {
        const int t = wv;
        #pragma unroll
        for (int s = 0; s < 2; ++s) {
            const float* wp = W + (size_t)(t * 16 + lr) * 128 + s * 32 + kg * 8;
            float4 f0 = *(const float4*)wp;
            float4 f1 = *(const float4*)(wp + 4);
            float4 g0 = *(const float4*)(wp + 64);
            float4 g1 = *(const float4*)(wp + 68);
            ldsW[t][s][0][l] = cvt_bf8(f0, f1);
            float4 d0 = make_float4(g0.x - f0.x, g0.y - f0.y, g0.z - f0.z, g0.w - f0.w);
            float4 d1 = make_float4(g1.x - f1.x, g1.y - f1.y, g1.z - f1.z, g1.w - f1.w);
            ldsW[t][s][1][l] = cvt_bf8(d0, d1);
        }
        if (tid < 64) ldsB[tid] = bias[tid];
    }
    __syncthreads();

    // read back W1 frags (stay register-resident) + bias
    bf16x8 b1[2][4];
    float  binit[4];
    #pragma unroll
    for (int t = 0; t < 4; ++t) {
        b1[0][t] = ldsW[t][0][0][l];
        b1[1][t] = ldsW[t][1][0][l];
        binit[t] = ldsB[t * 16 + lr];
    }

    // center: wave's 16 xs rows vs (W2-W1), bias-init. bd frags die here.
    const float* xsp = xs + ((size_t)bb * M_ + mblk + mw + lr) * 64 + kg * 8;
    bf16x8 axs0 = ld_bf8(xsp);
    bf16x8 axs1 = ld_bf8(xsp + 32);

    float vout[4][4];                  // [t][r]: o = t*16+lr, m = mw+kg*4+r
    #pragma unroll
    for (int t = 0; t < 4; ++t) {
        bf16x8 bd0 = ldsW[t][0][1][l];
        bf16x8 bd1 = ldsW[t][1][1][l];
        f32x4 a = {binit[t], binit[t], binit[t], binit[t]};
        a = __builtin_amdgcn_mfma_f32_16x16x32_bf16(axs0, bd0, a, 0, 0, 0);
        a = __builtin_amdgcn_mfma_f32_16x16x32_bf16(axs1, bd1, a, 0, 0, 0);
        vout[t][0] = a[0]; vout[t][1] = a[1];
        vout[t][2] = a[2]; vout[t][3] = a[3];
    }

    // ---- hoist ALL idx values to VGPRs (single lgkm wait)
    int rr[16];
    #pragma unroll
    for (int m = 0; m < 16; ++m)
        rr[m] = ldsI[(mw + m) * 16 + lr];

    const float* xb = x + (size_t)bb * N_ * 64;

    // ---- gather-max m-loop, distance-3 raw-float4 prefetch (full unroll,
    // all indices static -> registers, no scratch)
    float4 p0[16], p1[16], p2[16], p3[16];
    #pragma unroll
    for (int m = 0; m < 3; ++m) {
        const float* xp = xb + (size_t)(unsigned)rr[m] * 64 + kg * 8;
        p0[m] = *(const float4*)xp;
        p1[m] = *(const float4*)(xp + 4);
        p2[m] = *(const float4*)(xp + 32);
        p3[m] = *(const float4*)(xp + 36);
    }

    #pragma unroll
    for (int m = 0; m < 16; ++m) {
        if (m + 3 < 16) {
            const float* xp = xb + (size_t)(unsigned)rr[m + 3] * 64 + kg * 8;
            p0[m + 3] = *(const float4*)xp;
            p1[m + 3] = *(const float4*)(xp + 4);
            p2[m + 3] = *(const float4*)(xp + 32);
            p3[m + 3] = *(const float4*)(xp + 36);
        }
        bf16x8 a0 = cvt_bf8(p0[m], p1[m]);
        bf16x8 a1 = cvt_bf8(p2[m], p3[m]);
        #pragma unroll
        for (int t = 0; t < 4; ++t) {
            f32x4 a = {0.f, 0.f, 0.f, 0.f};
            a = __builtin_amdgcn_mfma_f32_16x16x32_bf16(a0, b1[0][t], a, 0, 0, 0);
            a = __builtin_amdgcn_mfma_f32_16x16x32_bf16(a1, b1[1][t], a, 0, 0, 0);
            float v = fmaxf(fmaxf(a[0], a[1]), fmaxf(a[2], a[3]));
            v = fmaxf(v, __shfl_xor(v, 16));
            v = fmaxf(v, __shfl_xor(v, 32));           // max over 16 k-rows
            if ((m >> 2) == kg)                        // owner lane-group
                vout[t][m & 3] += v;
        }
    }

    // relu + LDS transpose write: [o = t*16+lr][m = mw + kg*4 + r]
    #pragma unroll
    for (int t = 0; t < 4; ++t)
        #pragma unroll
        for (int r = 0; r < 4; ++r) {
            float v = vout[t][r];
            ldsT[(t * 16 + lr) * 65 + mw + kg * 4 + r] = v > 0.f ? v : 0.f;
        }
    __syncthreads();

    // coalesced stores: thread tid -> o = tid>>2, 16 m at (tid&3)*16
    const int o  = tid >> 2;
    const int ms = (tid & 3) * 16;
    float* op = out + ((size_t)bb * 64 + o) * M_ + mblk + ms;
    #pragma unroll
    for (int j = 0; j < 4; ++j) {
        const float* lp = &ldsT[o * 65 + ms + j * 4];
        *(float4*)(op + j * 4) = make_float4(lp[0], lp[1], lp[2], lp[3]);
    }
}

extern "C" void kernel_launch(void* const* d_in, const int* in_sizes, int n_in,
                              void* d_out, int out_size, void* d_ws, size_t ws_size,
                              hipStream_t stream) {
    const float* x    = (const float*)d_in[0];
    const float* xs   = (const float*)d_in[1];
    const int*   idx  = (const int*)d_in[2];
    const float* W    = (const float*)d_in[3];
    const float* bias = (const float*)d_in[4];
    float* out = (float*)d_out;

    // 512 blocks x 256 thr; block = 64 m, wave = 16 m
    fused_gconv<<<(B_ * M_) / 64, 256, 0, stream>>>(x, xs, idx, W, bias, out);
}